// Round 6
// baseline (930.000 us; speedup 1.0000x reference)
//
#include <hip/hip_runtime.h>
#include <hip/hip_bf16.h>
#include <math.h>

// Problem constants
#define BB 4
#define TT 1536
#define CC 1536
#define HH 8
#define DKk 64
#define DVv 192
#define NBASIS 32
#define LREL 3071          // 2T-1
#define MROWS 6144         // B*T

typedef short short8 __attribute__((ext_vector_type(8)));
typedef float floatx4 __attribute__((ext_vector_type(4)));

static __device__ inline short f2bf(float f) {
  __hip_bfloat16 h = __float2bfloat16(f);
  return *reinterpret_cast<short*>(&h);
}

// async global->LDS, 16B per lane; LDS dest = wave-uniform base + lane*16
static __device__ inline void gload_lds16(const __hip_bfloat16* g, __hip_bfloat16* l) {
  __builtin_amdgcn_global_load_lds(
      (const __attribute__((address_space(1))) unsigned int*)g,
      (__attribute__((address_space(3))) unsigned int*)l, 16, 0, 0);
}

// ---------------------------------------------------------------------------
// Stage 0: dtype detection (fp32 vs bf16 input payloads). See round-1 notes.
// ---------------------------------------------------------------------------
__global__ void detect_kernel(const void* __restrict__ x, int* __restrict__ flag) {
  if (threadIdx.x == 0 && blockIdx.x == 0) {
    const __hip_bfloat16* h = (const __hip_bfloat16*)x;
    int cnt = 0;
    for (int i = 0; i < 64; ++i) {
      float v = fabsf((float)h[2 * i]);
      if (v > 1e-5f && v < 256.0f) cnt++;
    }
    *flag = (cnt >= 32) ? 1 : 0;  // 1 => inputs are bf16
  }
}

__global__ __launch_bounds__(256) void convert_kernel(const void* __restrict__ src,
                                                      float* __restrict__ dst, int n,
                                                      const int* __restrict__ flag) {
  const int i = blockIdx.x * 256 + threadIdx.x;
  if (i >= n) return;
  if (*flag) dst[i] = (float)((const __hip_bfloat16*)src)[i];
  else       dst[i] = ((const float*)src)[i];
}

__global__ __launch_bounds__(256) void convbf_kernel(const void* __restrict__ src,
                                                     __hip_bfloat16* __restrict__ dst, int n,
                                                     const int* __restrict__ flag) {
  const int i = blockIdx.x * 256 + threadIdx.x;
  if (i >= n) return;
  if (*flag) dst[i] = ((const __hip_bfloat16*)src)[i];
  else       dst[i] = __float2bfloat16(((const float*)src)[i]);
}

// ---------------------------------------------------------------------------
// Weight transpose: src [K,N] (fp32/bf16 per flag) -> dst bf16 [N,K]
// ---------------------------------------------------------------------------
__global__ __launch_bounds__(256) void wt_kernel(const void* __restrict__ src,
                                                 __hip_bfloat16* __restrict__ dst,
                                                 int K, int N, const int* __restrict__ flag) {
  __shared__ __hip_bfloat16 tile[64][68];
  const int tid = threadIdx.x;
  const int k0 = blockIdx.y * 64, n0 = blockIdx.x * 64;
  const bool bf = (*flag != 0);
  {
    const int r = tid >> 2, c0 = (tid & 3) * 16;
    if (bf) {
      const __hip_bfloat16* sp = (const __hip_bfloat16*)src + (size_t)(k0 + r) * N + n0 + c0;
#pragma unroll
      for (int u = 0; u < 16; ++u) tile[r][c0 + u] = sp[u];
    } else {
      const float* sp = (const float*)src + (size_t)(k0 + r) * N + n0 + c0;
#pragma unroll
      for (int u = 0; u < 16; ++u) tile[r][c0 + u] = __float2bfloat16(sp[u]);
    }
  }
  __syncthreads();
  {
    const int nr = tid >> 2, c0 = (tid & 3) * 16;
    __hip_bfloat16* dp = dst + (size_t)(n0 + nr) * K + k0 + c0;
#pragma unroll
    for (int u = 0; u < 16; ++u) dp[u] = tile[c0 + u][nr];
  }
}

// ---------------------------------------------------------------------------
// Stage 1: gamma-basis max over pos (fp64). One block per basis j.
// ---------------------------------------------------------------------------
__global__ void gmax_kernel(double* __restrict__ gmax) {
  const int j = blockIdx.x;
  const double mean = 48.0 + 1488.0 * (double)j / 31.0;
  const double conc = (mean / 24.0) * (mean / 24.0);
  const double rate = mean / 576.0;
  const double log_norm = lgamma(conc) - conc * log(rate);
  double mx = 1e-8;
  for (int pos = 1 + threadIdx.x; pos <= 1535; pos += 256) {
    double p = exp((conc - 1.0) * log((double)pos) - rate * (double)pos - log_norm) + 1e-8;
    mx = fmax(mx, p);
  }
  __shared__ double red[256];
  red[threadIdx.x] = mx;
  __syncthreads();
  for (int s = 128; s > 0; s >>= 1) {
    if (threadIdx.x < s) red[threadIdx.x] = fmax(red[threadIdx.x], red[threadIdx.x + s]);
    __syncthreads();
  }
  if (threadIdx.x == 0) gmax[j] = red[0];
}

// ---------------------------------------------------------------------------
// Stage 2: pe[l, f], fp64 math, fp32 store.
// ---------------------------------------------------------------------------
__global__ void pe_kernel(float* __restrict__ pe, const double* __restrict__ gmax) {
  const int l = blockIdx.x;
  const int f = threadIdx.x;  // 0..191
  const int dist = l - (TT - 1);
  const int pos = dist < 0 ? -dist : dist;
  const int base = f % 96;
  const int cls = base / 32;
  const int j = base % 32;
  double v;
  if (cls == 0) {
    const double max_range = log(1536.0) / log(2.0);
    const double e = 3.0 + (max_range - 3.0) * (double)j / 31.0;
    const double hl = exp2(e);
    v = exp2(-(double)pos / hl);
  } else if (cls == 1) {
    const double width = exp2((double)(j + 1)) - 1.0;
    v = (width > (double)pos) ? 1.0 : 0.0;
  } else {
    const double mean = 48.0 + 1488.0 * (double)j / 31.0;
    const double conc = (mean / 24.0) * (mean / 24.0);
    const double rate = mean / 576.0;
    double p;
    if (pos == 0) {
      p = 1e-8;
    } else {
      const double log_norm = lgamma(conc) - conc * log(rate);
      p = exp((conc - 1.0) * log((double)pos) - rate * (double)pos - log_norm) + 1e-8;
    }
    v = p / gmax[j];
  }
  float out = (float)v;
  if (f >= 96) {
    float sgn = (dist > 0) ? 1.f : (dist < 0 ? -1.f : 0.f);
    out *= sgn;
  }
  pe[(size_t)l * 192 + f] = out;
}

// ---------------------------------------------------------------------------
// Stage 3: rKl[h][l][d] (bf16) = sum_f pe[l,f] * W_rel_k[f, h*64+d]
// ---------------------------------------------------------------------------
__global__ __launch_bounds__(512) void relk_kernel(const float* __restrict__ pe,
                                                   const float* __restrict__ Wrk,
                                                   __hip_bfloat16* __restrict__ rKl) {
  __shared__ float pes[8][192];
  const int l0 = blockIdx.x * 8;
  const int nrows = (LREL - l0) < 8 ? (LREL - l0) : 8;
  const int tid = threadIdx.x;
  for (int idx = tid; idx < nrows * 192; idx += 512) {
    int r = idx / 192, f = idx % 192;
    pes[r][f] = pe[(size_t)(l0 + r) * 192 + f];
  }
  __syncthreads();
  float acc[8] = {0.f, 0.f, 0.f, 0.f, 0.f, 0.f, 0.f, 0.f};
  for (int f = 0; f < 192; ++f) {
    float w = Wrk[(size_t)f * 512 + tid];
#pragma unroll
    for (int r = 0; r < 8; ++r) acc[r] += pes[r][f] * w;
  }
  const int h = tid >> 6, d = tid & 63;
  for (int r = 0; r < nrows; ++r)
    rKl[((size_t)h * LREL + (l0 + r)) * 64 + d] = __float2bfloat16(acc[r]);
}

// ---------------------------------------------------------------------------
// bf16 MFMA GEMM (m97 structure): C[M,N] = A[M,K] @ Bt[N,K]^T
// 128x128 tile, BK=32, 4 waves, global_load_lds staging, ds_read_b128 frags.
// MODE 0: fp32 out; 1: bf16 out; 2: d_out per flag (+bias).
// ---------------------------------------------------------------------------
template <int MODE, bool BIAS>
__global__ __launch_bounds__(256) void gemm_mfma(const __hip_bfloat16* __restrict__ A,
                                                 const __hip_bfloat16* __restrict__ Bt,
                                                 void* __restrict__ Cout,
                                                 const float* __restrict__ bias,
                                                 int M, int N, int K,
                                                 const int* __restrict__ flag) {
  __shared__ __align__(16) __hip_bfloat16 As[128 * 32];
  __shared__ __align__(16) __hip_bfloat16 Bs[128 * 32];
  const int tid = threadIdx.x;
  const int w = tid >> 6, lane = tid & 63;
  const int quad = lane >> 4, l16 = lane & 15;
  const int wm = w >> 1, wn = w & 1;
  const int row0 = blockIdx.y * 128, col0 = blockIdx.x * 128;

  const floatx4 vzero = {0.f, 0.f, 0.f, 0.f};
  floatx4 acc[4][4];
#pragma unroll
  for (int i = 0; i < 4; ++i)
#pragma unroll
    for (int j = 0; j < 4; ++j) acc[i][j] = vzero;

  const int sr = lane >> 2;            // 0..15
  const int sc = (lane & 3) * 8;       // bf16 elems
  const __hip_bfloat16* ag0 = A + (size_t)(row0 + w * 32 + sr) * K + sc;
  const __hip_bfloat16* ag1 = A + (size_t)(row0 + w * 32 + 16 + sr) * K + sc;
  const __hip_bfloat16* bg0 = Bt + (size_t)(col0 + w * 32 + sr) * K + sc;
  const __hip_bfloat16* bg1 = Bt + (size_t)(col0 + w * 32 + 16 + sr) * K + sc;
  __hip_bfloat16* as0 = As + w * 32 * 32;
  __hip_bfloat16* as1 = As + (w * 32 + 16) * 32;
  __hip_bfloat16* bs0 = Bs + w * 32 * 32;
  __hip_bfloat16* bs1 = Bs + (w * 32 + 16) * 32;

  for (int k0 = 0; k0 < K; k0 += 32) {
    __syncthreads();
    gload_lds16(ag0 + k0, as0);
    gload_lds16(ag1 + k0, as1);
    gload_lds16(bg0 + k0, bs0);
    gload_lds16(bg1 + k0, bs1);
    __syncthreads();
    short8 aF[4], bF[4];
#pragma unroll
    for (int mt = 0; mt < 4; ++mt)
      aF[mt] = *(const short8*)(As + (wm * 64 + mt * 16 + l16) * 32 + quad * 8);
#pragma unroll
    for (int nt = 0; nt < 4; ++nt)
      bF[nt] = *(const short8*)(Bs + (wn * 64 + nt * 16 + l16) * 32 + quad * 8);
#pragma unroll
    for (int mt = 0; mt < 4; ++mt)
#pragma unroll
      for (int nt = 0; nt < 4; ++nt)
        acc[mt][nt] = __builtin_amdgcn_mfma_f32_16x16x32_bf16(aF[mt], bF[nt], acc[mt][nt], 0, 0, 0);
  }

  const bool obf = (MODE == 2) ? (*flag != 0) : false;
#pragma unroll
  for (int mt = 0; mt < 4; ++mt) {
#pragma unroll
    for (int r = 0; r < 4; ++r) {
      const int row = row0 + wm * 64 + mt * 16 + quad * 4 + r;
#pragma unroll
      for (int nt = 0; nt < 4; ++nt) {
        const int col = col0 + wn * 64 + nt * 16 + l16;
        float v = acc[mt][nt][r];
        if (BIAS) v += bias[col];
        if (MODE == 0) {
          ((float*)Cout)[(size_t)row * N + col] = v;
        } else if (MODE == 1) {
          ((__hip_bfloat16*)Cout)[(size_t)row * N + col] = __float2bfloat16(v);
        } else {
          if (obf) ((__hip_bfloat16*)Cout)[(size_t)row * N + col] = __float2bfloat16(v);
          else     ((float*)Cout)[(size_t)row * N + col] = v;
        }
      }
    }
  }
}

// ---------------------------------------------------------------------------
// V transpose: Vbf bf16 [b*T+t][h*192+v] -> Vtg bf16 [(b*8+h)*192 + v][1536 t]
// ---------------------------------------------------------------------------
__global__ __launch_bounds__(256) void vtrans_kernel(const __hip_bfloat16* __restrict__ Vbf,
                                                     __hip_bfloat16* __restrict__ Vtg) {
  int bid = blockIdx.x;            // 4*8*24*3 = 2304
  int vt = bid % 3; int tt = (bid / 3) % 24; int h = (bid / 72) & 7; int b = bid / 576;
  __shared__ __hip_bfloat16 tile[64][72];
  const int tid = threadIdx.x;
  {
    int r = tid >> 2, c0 = (tid & 3) * 16;   // r: t-row, c: v-col
    const __hip_bfloat16* src = Vbf + (size_t)(b * TT + tt * 64 + r) * 1536 + h * 192 + vt * 64 + c0;
#pragma unroll
    for (int u = 0; u < 16; ++u) tile[r][c0 + u] = src[u];
  }
  __syncthreads();
  {
    int vr = tid >> 2, t0 = (tid & 3) * 16;
    __hip_bfloat16* dst = Vtg + ((size_t)((b * 8 + h) * 192) + vt * 64 + vr) * 1536 + tt * 64 + t0;
    union { uint4 u4[2]; unsigned short us[16]; } pk;
#pragma unroll
    for (int u = 0; u < 16; ++u) pk.us[u] = *(const unsigned short*)&tile[t0 + u][vr];
    *(uint4*)(dst) = pk.u4[0];
    *(uint4*)(dst + 8) = pk.u4[1];
  }
}

// ---------------------------------------------------------------------------
// MFMA flash attention. Block = (b, h, 64-row q tile); 4 waves, 256 thr.
// 3 barriers per k-tile; rel shift done via in-register shuffles.
// ---------------------------------------------------------------------------
__global__ __launch_bounds__(256, 3) void attn_mfma(
    const float* __restrict__ tmpQ,                 // [b*T+t][512] fp32
    const float* __restrict__ rwb,                  // [512]
    const float* __restrict__ rrb,                  // [512]
    const __hip_bfloat16* __restrict__ Kbf,         // [b*T+t][512] bf16
    const __hip_bfloat16* __restrict__ rKl,         // [h*3071+l][64] bf16
    const __hip_bfloat16* __restrict__ Vtg,         // [(b*8+h)*192+v][1536] bf16
    __hip_bfloat16* __restrict__ O)                 // [b*T+q][1536] bf16
{
  const int tid = threadIdx.x;
  const int w = tid >> 6, lane = tid & 63;
  const int quad = lane >> 4, l16 = lane & 15;
  const int bid = blockIdx.x;
  const int qt = bid % 24;
  const int h = (bid / 24) & 7;
  const int b = bid / 192;
  const int q0 = qt * 64;

  // LDS: Ktile 64x68 (8704 B) @0 ; rKwin 128x68 (17408 B) @8704 ;
  //      Vtile 192x68 (26112 B) @26112.  Total 52224 -> 3 blocks/CU.
  //      Ptile aliases Ktile (P written after B3; wave-private rows).
  __shared__ __align__(16) char sm[52224];
  __hip_bfloat16* Ktile = (__hip_bfloat16*)sm;
  __hip_bfloat16* Ptile = (__hip_bfloat16*)sm;
  __hip_bfloat16* rKwin = (__hip_bfloat16*)(sm + 8704);
  __hip_bfloat16* Vtile = (__hip_bfloat16*)(sm + 26112);

  // Q fragments (A-layout): lane holds A[m=l16][k=quad*8+j], kstep*32 offset.
  short8 aQw[2], aQr[2];
  {
    const int qrow = q0 + w * 16 + l16;
    const float* qp = tmpQ + (size_t)(b * TT + qrow) * 512 + h * 64;
#pragma unroll
    for (int ks = 0; ks < 2; ++ks) {
#pragma unroll
      for (int j = 0; j < 8; ++j) {
        const int d = ks * 32 + quad * 8 + j;
        const float qv = qp[d] * 0.125f;
        aQw[ks][j] = f2bf(qv + rwb[h * 64 + d]);
        aQr[ks][j] = f2bf(qv + rrb[h * 64 + d]);
      }
    }
  }

  const floatx4 vzero = {0.f, 0.f, 0.f, 0.f};
  floatx4 Oacc[12];
#pragma unroll
  for (int i = 0; i < 12; ++i) Oacc[i] = vzero;
  float mrow[4], lrow[4];
#pragma unroll
  for (int r = 0; r < 4; ++r) { mrow[r] = -INFINITY; lrow[r] = 0.f; }

  const size_t kBase = (size_t)(b * TT) * 512 + h * 64;
  const __hip_bfloat16* VtgB = Vtg + ((size_t)(b * 8 + h) * 192) * 1536;
  const int l0base = 1472 - q0;   // l = l0base + k0 + j

  for (int k0 = 0; k0 < TT; k0 += 64) {
    __syncthreads();  // B1: prev-iter Ptile/Vtile reads done
    {   // stage Ktile (64x64, stride 68)
      const int r = tid >> 2, c0 = (tid & 3) * 16;
      const __hip_bfloat16* src = Kbf + kBase + (size_t)(k0 + r) * 512 + c0;
      *(uint4*)(Ktile + r * 68 + c0)     = *(const uint4*)(src);
      *(uint4*)(Ktile + r * 68 + c0 + 8) = *(const uint4*)(src + 8);
    }
    {   // stage rKwin (128x64, stride 68)
      const int r = tid >> 1, c0 = (tid & 1) * 32;
      int l = l0base + k0 + r;
      l = l < 3070 ? l : 3070;   // rows with j>126 are never consumed; clamp
      const __hip_bfloat16* src = rKl + ((size_t)h * LREL + l) * 64 + c0;
#pragma unroll
      for (int u = 0; u < 4; ++u)
        *(uint4*)(rKwin + r * 68 + c0 + u * 8) = *(const uint4*)(src + u * 8);
    }
    {   // stage Vtile (192x64, stride 68) — full DV in one pass
      for (int i = tid; i < 192 * 8; i += 256) {
        const int r = i >> 3, c0 = (i & 7) * 8;
        *(uint4*)(Vtile + r * 68 + c0) =
            *(const uint4*)(VtgB + (size_t)r * 1536 + k0 + c0);
      }
    }
    __syncthreads();  // B2: tiles visible

    floatx4 S[4], R[8];
#pragma unroll
    for (int i = 0; i < 4; ++i) S[i] = vzero;
#pragma unroll
    for (int i = 0; i < 8; ++i) R[i] = vzero;
#pragma unroll
    for (int kt = 0; kt < 4; ++kt) {
#pragma unroll
      for (int ks = 0; ks < 2; ++ks) {
        short8 bK = *(const short8*)(Ktile + (kt * 16 + l16) * 68 + ks * 32 + quad * 8);
        S[kt] = __builtin_amdgcn_mfma_f32_16x16x32_bf16(aQw[ks], bK, S[kt], 0, 0, 0);
      }
    }
#pragma unroll
    for (int jt = 0; jt < 8; ++jt) {
#pragma unroll
      for (int ks = 0; ks < 2; ++ks) {
        short8 bR = *(const short8*)(rKwin + (jt * 16 + l16) * 68 + ks * 32 + quad * 8);
        R[jt] = __builtin_amdgcn_mfma_f32_16x16x32_bf16(aQr[ks], bR, R[jt], 0, 0, 0);
      }
    }

    // shift-gather via shuffles: S[kt][r] += R(row, kt*16 + l16 + 63 - row),
    // row = w*16 + quad*4 + r. Source lane = quad*16 + ((l16 + 15-quad*4-r)&15);
    // source reg = kt + (3-w) + carry. (3-w) is wave-uniform -> branch on w.
#pragma unroll
    for (int cw = 0; cw < 4; ++cw) {
      if (w == cw) {
        const int c = 3 - cw;
#pragma unroll
        for (int r = 0; r < 4; ++r) {
          const int a_r = 15 - quad * 4 - r;        // in [0,15]
          const int t = l16 + a_r;                  // in [0,30]
          const int srclane = quad * 16 + (t & 15);
          float g[5];
#pragma unroll
          for (int u = 0; u < 5; ++u)
            g[u] = __shfl(R[c + u][r], srclane);    // c+u <= 7
          const bool carry = t >= 16;
#pragma unroll
          for (int kt = 0; kt < 4; ++kt)
            S[kt][r] += carry ? g[kt + 1] : g[kt];
        }
      }
    }

    // online softmax (rows wave-private; 16 lanes share a row)
    float alpha[4];
#pragma unroll
    for (int r = 0; r < 4; ++r) {
      float mx = fmaxf(fmaxf(S[0][r], S[1][r]), fmaxf(S[2][r], S[3][r]));
#pragma unroll
      for (int off = 8; off > 0; off >>= 1) mx = fmaxf(mx, __shfl_xor(mx, off));
      const float nm = fmaxf(mrow[r], mx);
      alpha[r] = __expf(mrow[r] - nm);
      mrow[r] = nm;
      float ps = 0.f;
#pragma unroll
      for (int kt = 0; kt < 4; ++kt) {
        const float p = __expf(S[kt][r] - nm);
        S[kt][r] = p;
        ps += p;
      }
#pragma unroll
      for (int off = 8; off > 0; off >>= 1) ps += __shfl_xor(ps, off);
      lrow[r] = lrow[r] * alpha[r] + ps;
    }

    __syncthreads();  // B3: all K/rK frag reads done; Ptile may overwrite Ktile

    // write P (wave-private rows; aP read below is same-wave, DS in-order)
#pragma unroll
    for (int kt = 0; kt < 4; ++kt) {
#pragma unroll
      for (int r = 0; r < 4; ++r) {
        const int row = w * 16 + quad * 4 + r;
        Ptile[row * 68 + kt * 16 + l16] = __float2bfloat16(S[kt][r]);
      }
    }
#pragma unroll
    for (int vt = 0; vt < 12; ++vt)
#pragma unroll
      for (int r = 0; r < 4; ++r) Oacc[vt][r] *= alpha[r];

    short8 aP[2];
#pragma unroll
    for (int ks = 0; ks < 2; ++ks)
      aP[ks] = *(const short8*)(Ptile + (w * 16 + l16) * 68 + ks * 32 + quad * 8);
#pragma unroll
    for (int vt = 0; vt < 12; ++vt) {
#pragma unroll
      for (int ks = 0; ks < 2; ++ks) {
        short8 bV = *(const short8*)(Vtile + (vt * 16 + l16) * 68 + ks * 32 + quad * 8);
        Oacc[vt] = __builtin_amdgcn_mfma_f32_16x16x32_bf16(aP[ks], bV, Oacc[vt], 0, 0, 0);
      }
    }
  }

  // epilogue: normalize, store bf16 (feeds MFMA out-projection)
#pragma unroll
  for (int r = 0; r < 4; ++r) {
    const float inv = 1.f / lrow[r];
    const int qrow = q0 + w * 16 + quad * 4 + r;
    __hip_bfloat16* op = O + (size_t)(b * TT + qrow) * 1536 + h * 192;
#pragma unroll
    for (int vt = 0; vt < 12; ++vt)
      op[vt * 16 + l16] = __float2bfloat16(Oacc[vt][r] * inv);
  }
}

// ---------------------------------------------------------------------------
extern "C" void kernel_launch(void* const* d_in, const int* in_sizes, int n_in,
                              void* d_out, int out_size, void* d_ws, size_t ws_size,
                              hipStream_t stream) {
  const void* x     = d_in[0];
  const void* W_q   = d_in[1];
  const void* W_k   = d_in[2];
  const void* W_v   = d_in[3];
  const void* W_rel = d_in[4];
  const void* W_out = d_in[5];
  const void* b_out = d_in[6];
  const void* r_w_b = d_in[7];
  const void* r_r_b = d_in[8];

  float* ws = (float*)d_ws;
  int*    flag = (int*)d_ws;                     // 16 floats reserved
  double* gmax = (double*)(ws + 16);             // 64 floats
  float* pe    = ws + 16 + 64;                   // 3071*192
  float* WrelF = pe    + (size_t)LREL * 192;     // 192*512
  float* boutF = WrelF + (size_t)192 * 512;      // 1536
  float* rwbF  = boutF + 1536;                   // 512
  float* rrbF  = rwbF + 512;                     // 512
  float* tmpQ  = rrbF + 512;                     // 6144*512 fp32
  __hip_bfloat16* xBf  = (__hip_bfloat16*)(tmpQ + (size_t)MROWS * 512);  // 6144*1536
  __hip_bfloat16* WqT  = xBf  + (size_t)MROWS * 1536;     // 512*1536
  __hip_bfloat16* WkT  = WqT  + (size_t)512 * 1536;       // 512*1536
  __hip_bfloat16* WvT  = WkT  + (size_t)512 * 1536;       // 1536*1536
  __hip_bfloat16* WoT  = WvT  + (size_t)1536 * 1536;      // 1536*1536
  __hip_bfloat16* Kbf  = WoT  + (size_t)1536 * 1536;      // 6144*512
  __hip_bfloat16* Vbf  = Kbf  + (size_t)MROWS * 512;      // 6144*1536
  __hip_bfloat16* Vtg  = Vbf  + (size_t)MROWS * 1536;     // 32*192*1536
  __hip_bfloat16* Obf  = Vtg  + (size_t)32 * 192 * 1536;  // 6144*1536
  __hip_bfloat16* rKl  = Obf  + (size_t)MROWS * 1536;     // 8*3071*64
  char* endp = (char*)(rKl + (size_t)HH * LREL * 64);
  if (ws_size < (size_t)(endp - (char*)d_ws)) return;  // ws too small

  detect_kernel<<<1, 64, 0, stream>>>(x, flag);

  auto conv = [&](const void* src, float* dst, int n) {
    convert_kernel<<<(n + 255) / 256, 256, 0, stream>>>(src, dst, n, flag);
  };
  conv(W_rel, WrelF, 192 * 512);
  conv(b_out, boutF, 1536);
  conv(r_w_b, rwbF,  512);
  conv(r_r_b, rrbF,  512);

  convbf_kernel<<<(MROWS * 1536 + 255) / 256, 256, 0, stream>>>(x, xBf, MROWS * 1536, flag);

  // weight transposes: src [K,N] -> dst [N,K] bf16
  wt_kernel<<<dim3(512 / 64, 1536 / 64), 256, 0, stream>>>(W_q, WqT, 1536, 512, flag);
  wt_kernel<<<dim3(512 / 64, 1536 / 64), 256, 0, stream>>>(W_k, WkT, 1536, 512, flag);
  wt_kernel<<<dim3(1536 / 64, 1536 / 64), 256, 0, stream>>>(W_v, WvT, 1536, 1536, flag);
  wt_kernel<<<dim3(1536 / 64, 1536 / 64), 256, 0, stream>>>(W_out, WoT, 1536, 1536, flag);

  gmax_kernel<<<32, 256, 0, stream>>>(gmax);
  pe_kernel<<<LREL, 192, 0, stream>>>(pe, gmax);
  relk_kernel<<<(LREL + 7) / 8, 512, 0, stream>>>(pe, WrelF, rKl);

  // projections (bf16 MFMA)
  gemm_mfma<0, false><<<dim3(512 / 128, MROWS / 128), 256, 0, stream>>>(
      xBf, WqT, tmpQ, nullptr, MROWS, 512, CC, flag);
  gemm_mfma<1, false><<<dim3(512 / 128, MROWS / 128), 256, 0, stream>>>(
      xBf, WkT, Kbf, nullptr, MROWS, 512, CC, flag);
  gemm_mfma<1, false><<<dim3(1536 / 128, MROWS / 128), 256, 0, stream>>>(
      xBf, WvT, Vbf, nullptr, MROWS, 1536, CC, flag);

  vtrans_kernel<<<2304, 256, 0, stream>>>(Vbf, Vtg);

  attn_mfma<<<768, 256, 0, stream>>>(tmpQ, rwbF, rrbF, Kbf, rKl, Vtg, Obf);

  gemm_mfma<2, true><<<dim3(1536 / 128, MROWS / 128), 256, 0, stream>>>(
      Obf, WoT, d_out, boutF, MROWS, 1536, CC, flag);
}

// Round 7
// 913.497 us; speedup vs baseline: 1.0181x; 1.0181x over previous
//
#include <hip/hip_runtime.h>
#include <hip/hip_bf16.h>
#include <math.h>

// Problem constants
#define BB 4
#define TT 1536
#define CC 1536
#define HH 8
#define DKk 64
#define DVv 192
#define NBASIS 32
#define LREL 3071          // 2T-1
#define MROWS 6144         // B*T

typedef short short8 __attribute__((ext_vector_type(8)));
typedef float floatx4 __attribute__((ext_vector_type(4)));

static __device__ inline short f2bf(float f) {
  __hip_bfloat16 h = __float2bfloat16(f);
  return *reinterpret_cast<short*>(&h);
}

// async global->LDS, 16B per lane; LDS dest = wave-uniform base + lane*16
static __device__ inline void gload_lds16(const __hip_bfloat16* g, __hip_bfloat16* l) {
  __builtin_amdgcn_global_load_lds(
      (const __attribute__((address_space(1))) unsigned int*)g,
      (__attribute__((address_space(3))) unsigned int*)l, 16, 0, 0);
}

// ---------------------------------------------------------------------------
// Stage 0: dtype detection (fp32 vs bf16 input payloads). See round-1 notes.
// ---------------------------------------------------------------------------
__global__ void detect_kernel(const void* __restrict__ x, int* __restrict__ flag) {
  if (threadIdx.x == 0 && blockIdx.x == 0) {
    const __hip_bfloat16* h = (const __hip_bfloat16*)x;
    int cnt = 0;
    for (int i = 0; i < 64; ++i) {
      float v = fabsf((float)h[2 * i]);
      if (v > 1e-5f && v < 256.0f) cnt++;
    }
    *flag = (cnt >= 32) ? 1 : 0;  // 1 => inputs are bf16
  }
}

__global__ __launch_bounds__(256) void convert_kernel(const void* __restrict__ src,
                                                      float* __restrict__ dst, int n,
                                                      const int* __restrict__ flag) {
  const int i = blockIdx.x * 256 + threadIdx.x;
  if (i >= n) return;
  if (*flag) dst[i] = (float)((const __hip_bfloat16*)src)[i];
  else       dst[i] = ((const float*)src)[i];
}

__global__ __launch_bounds__(256) void convbf_kernel(const void* __restrict__ src,
                                                     __hip_bfloat16* __restrict__ dst, int n,
                                                     const int* __restrict__ flag) {
  const int i = blockIdx.x * 256 + threadIdx.x;
  if (i >= n) return;
  if (*flag) dst[i] = ((const __hip_bfloat16*)src)[i];
  else       dst[i] = __float2bfloat16(((const float*)src)[i]);
}

// ---------------------------------------------------------------------------
// Weight transpose: src [K,N] (fp32/bf16 per flag) -> dst bf16 [N,K]
// ---------------------------------------------------------------------------
__global__ __launch_bounds__(256) void wt_kernel(const void* __restrict__ src,
                                                 __hip_bfloat16* __restrict__ dst,
                                                 int K, int N, const int* __restrict__ flag) {
  __shared__ __hip_bfloat16 tile[64][68];
  const int tid = threadIdx.x;
  const int k0 = blockIdx.y * 64, n0 = blockIdx.x * 64;
  const bool bf = (*flag != 0);
  {
    const int r = tid >> 2, c0 = (tid & 3) * 16;
    if (bf) {
      const __hip_bfloat16* sp = (const __hip_bfloat16*)src + (size_t)(k0 + r) * N + n0 + c0;
#pragma unroll
      for (int u = 0; u < 16; ++u) tile[r][c0 + u] = sp[u];
    } else {
      const float* sp = (const float*)src + (size_t)(k0 + r) * N + n0 + c0;
#pragma unroll
      for (int u = 0; u < 16; ++u) tile[r][c0 + u] = __float2bfloat16(sp[u]);
    }
  }
  __syncthreads();
  {
    const int nr = tid >> 2, c0 = (tid & 3) * 16;
    __hip_bfloat16* dp = dst + (size_t)(n0 + nr) * K + k0 + c0;
#pragma unroll
    for (int u = 0; u < 16; ++u) dp[u] = tile[c0 + u][nr];
  }
}

// ---------------------------------------------------------------------------
// Stage 1: gamma-basis max over pos (fp64). One block per basis j.
// ---------------------------------------------------------------------------
__global__ void gmax_kernel(double* __restrict__ gmax) {
  const int j = blockIdx.x;
  const double mean = 48.0 + 1488.0 * (double)j / 31.0;
  const double conc = (mean / 24.0) * (mean / 24.0);
  const double rate = mean / 576.0;
  const double log_norm = lgamma(conc) - conc * log(rate);
  double mx = 1e-8;
  for (int pos = 1 + threadIdx.x; pos <= 1535; pos += 256) {
    double p = exp((conc - 1.0) * log((double)pos) - rate * (double)pos - log_norm) + 1e-8;
    mx = fmax(mx, p);
  }
  __shared__ double red[256];
  red[threadIdx.x] = mx;
  __syncthreads();
  for (int s = 128; s > 0; s >>= 1) {
    if (threadIdx.x < s) red[threadIdx.x] = fmax(red[threadIdx.x], red[threadIdx.x + s]);
    __syncthreads();
  }
  if (threadIdx.x == 0) gmax[j] = red[0];
}

// ---------------------------------------------------------------------------
// Stage 2: pe[l, f], fp64 math, fp32 store.
// ---------------------------------------------------------------------------
__global__ void pe_kernel(float* __restrict__ pe, const double* __restrict__ gmax) {
  const int l = blockIdx.x;
  const int f = threadIdx.x;  // 0..191
  const int dist = l - (TT - 1);
  const int pos = dist < 0 ? -dist : dist;
  const int base = f % 96;
  const int cls = base / 32;
  const int j = base % 32;
  double v;
  if (cls == 0) {
    const double max_range = log(1536.0) / log(2.0);
    const double e = 3.0 + (max_range - 3.0) * (double)j / 31.0;
    const double hl = exp2(e);
    v = exp2(-(double)pos / hl);
  } else if (cls == 1) {
    const double width = exp2((double)(j + 1)) - 1.0;
    v = (width > (double)pos) ? 1.0 : 0.0;
  } else {
    const double mean = 48.0 + 1488.0 * (double)j / 31.0;
    const double conc = (mean / 24.0) * (mean / 24.0);
    const double rate = mean / 576.0;
    double p;
    if (pos == 0) {
      p = 1e-8;
    } else {
      const double log_norm = lgamma(conc) - conc * log(rate);
      p = exp((conc - 1.0) * log((double)pos) - rate * (double)pos - log_norm) + 1e-8;
    }
    v = p / gmax[j];
  }
  float out = (float)v;
  if (f >= 96) {
    float sgn = (dist > 0) ? 1.f : (dist < 0 ? -1.f : 0.f);
    out *= sgn;
  }
  pe[(size_t)l * 192 + f] = out;
}

// ---------------------------------------------------------------------------
// Stage 3: rKl[h][l][d] (bf16) = sum_f pe[l,f] * W_rel_k[f, h*64+d]
// ---------------------------------------------------------------------------
__global__ __launch_bounds__(512) void relk_kernel(const float* __restrict__ pe,
                                                   const float* __restrict__ Wrk,
                                                   __hip_bfloat16* __restrict__ rKl) {
  __shared__ float pes[8][192];
  const int l0 = blockIdx.x * 8;
  const int nrows = (LREL - l0) < 8 ? (LREL - l0) : 8;
  const int tid = threadIdx.x;
  for (int idx = tid; idx < nrows * 192; idx += 512) {
    int r = idx / 192, f = idx % 192;
    pes[r][f] = pe[(size_t)(l0 + r) * 192 + f];
  }
  __syncthreads();
  float acc[8] = {0.f, 0.f, 0.f, 0.f, 0.f, 0.f, 0.f, 0.f};
  for (int f = 0; f < 192; ++f) {
    float w = Wrk[(size_t)f * 512 + tid];
#pragma unroll
    for (int r = 0; r < 8; ++r) acc[r] += pes[r][f] * w;
  }
  const int h = tid >> 6, d = tid & 63;
  for (int r = 0; r < nrows; ++r)
    rKl[((size_t)h * LREL + (l0 + r)) * 64 + d] = __float2bfloat16(acc[r]);
}

// ---------------------------------------------------------------------------
// bf16 MFMA GEMM (m97 structure): C[M,N] = A[M,K] @ Bt[N,K]^T
// 128x128 tile, BK=32, 4 waves, global_load_lds staging, ds_read_b128 frags.
// MODE 0: fp32 out; 1: bf16 out; 2: d_out per flag (+bias).
// ---------------------------------------------------------------------------
template <int MODE, bool BIAS>
__global__ __launch_bounds__(256) void gemm_mfma(const __hip_bfloat16* __restrict__ A,
                                                 const __hip_bfloat16* __restrict__ Bt,
                                                 void* __restrict__ Cout,
                                                 const float* __restrict__ bias,
                                                 int M, int N, int K,
                                                 const int* __restrict__ flag) {
  __shared__ __align__(16) __hip_bfloat16 As[128 * 32];
  __shared__ __align__(16) __hip_bfloat16 Bs[128 * 32];
  const int tid = threadIdx.x;
  const int w = tid >> 6, lane = tid & 63;
  const int quad = lane >> 4, l16 = lane & 15;
  const int wm = w >> 1, wn = w & 1;
  const int row0 = blockIdx.y * 128, col0 = blockIdx.x * 128;

  const floatx4 vzero = {0.f, 0.f, 0.f, 0.f};
  floatx4 acc[4][4];
#pragma unroll
  for (int i = 0; i < 4; ++i)
#pragma unroll
    for (int j = 0; j < 4; ++j) acc[i][j] = vzero;

  const int sr = lane >> 2;            // 0..15
  const int sc = (lane & 3) * 8;       // bf16 elems
  const __hip_bfloat16* ag0 = A + (size_t)(row0 + w * 32 + sr) * K + sc;
  const __hip_bfloat16* ag1 = A + (size_t)(row0 + w * 32 + 16 + sr) * K + sc;
  const __hip_bfloat16* bg0 = Bt + (size_t)(col0 + w * 32 + sr) * K + sc;
  const __hip_bfloat16* bg1 = Bt + (size_t)(col0 + w * 32 + 16 + sr) * K + sc;
  __hip_bfloat16* as0 = As + w * 32 * 32;
  __hip_bfloat16* as1 = As + (w * 32 + 16) * 32;
  __hip_bfloat16* bs0 = Bs + w * 32 * 32;
  __hip_bfloat16* bs1 = Bs + (w * 32 + 16) * 32;

  for (int k0 = 0; k0 < K; k0 += 32) {
    __syncthreads();
    gload_lds16(ag0 + k0, as0);
    gload_lds16(ag1 + k0, as1);
    gload_lds16(bg0 + k0, bs0);
    gload_lds16(bg1 + k0, bs1);
    __syncthreads();
    short8 aF[4], bF[4];
#pragma unroll
    for (int mt = 0; mt < 4; ++mt)
      aF[mt] = *(const short8*)(As + (wm * 64 + mt * 16 + l16) * 32 + quad * 8);
#pragma unroll
    for (int nt = 0; nt < 4; ++nt)
      bF[nt] = *(const short8*)(Bs + (wn * 64 + nt * 16 + l16) * 32 + quad * 8);
#pragma unroll
    for (int mt = 0; mt < 4; ++mt)
#pragma unroll
      for (int nt = 0; nt < 4; ++nt)
        acc[mt][nt] = __builtin_amdgcn_mfma_f32_16x16x32_bf16(aF[mt], bF[nt], acc[mt][nt], 0, 0, 0);
  }

  const bool obf = (MODE == 2) ? (*flag != 0) : false;
#pragma unroll
  for (int mt = 0; mt < 4; ++mt) {
#pragma unroll
    for (int r = 0; r < 4; ++r) {
      const int row = row0 + wm * 64 + mt * 16 + quad * 4 + r;
#pragma unroll
      for (int nt = 0; nt < 4; ++nt) {
        const int col = col0 + wn * 64 + nt * 16 + l16;
        float v = acc[mt][nt][r];
        if (BIAS) v += bias[col];
        if (MODE == 0) {
          ((float*)Cout)[(size_t)row * N + col] = v;
        } else if (MODE == 1) {
          ((__hip_bfloat16*)Cout)[(size_t)row * N + col] = __float2bfloat16(v);
        } else {
          if (obf) ((__hip_bfloat16*)Cout)[(size_t)row * N + col] = __float2bfloat16(v);
          else     ((float*)Cout)[(size_t)row * N + col] = v;
        }
      }
    }
  }
}

// ---------------------------------------------------------------------------
// V transpose: Vbf bf16 [b*T+t][h*192+v] -> Vtg bf16 [(b*8+h)*192 + v][1536 t]
// ---------------------------------------------------------------------------
__global__ __launch_bounds__(256) void vtrans_kernel(const __hip_bfloat16* __restrict__ Vbf,
                                                     __hip_bfloat16* __restrict__ Vtg) {
  int bid = blockIdx.x;            // 4*8*24*3 = 2304
  int vt = bid % 3; int tt = (bid / 3) % 24; int h = (bid / 72) & 7; int b = bid / 576;
  __shared__ __hip_bfloat16 tile[64][72];
  const int tid = threadIdx.x;
  {
    int r = tid >> 2, c0 = (tid & 3) * 16;   // r: t-row, c: v-col
    const __hip_bfloat16* src = Vbf + (size_t)(b * TT + tt * 64 + r) * 1536 + h * 192 + vt * 64 + c0;
#pragma unroll
    for (int u = 0; u < 16; ++u) tile[r][c0 + u] = src[u];
  }
  __syncthreads();
  {
    int vr = tid >> 2, t0 = (tid & 3) * 16;
    __hip_bfloat16* dst = Vtg + ((size_t)((b * 8 + h) * 192) + vt * 64 + vr) * 1536 + tt * 64 + t0;
    union { uint4 u4[2]; unsigned short us[16]; } pk;
#pragma unroll
    for (int u = 0; u < 16; ++u) pk.us[u] = *(const unsigned short*)&tile[t0 + u][vr];
    *(uint4*)(dst) = pk.u4[0];
    *(uint4*)(dst + 8) = pk.u4[1];
  }
}

// ---------------------------------------------------------------------------
// MFMA flash attention. Block = (b, h, 64-row q tile); 4 waves, 256 thr.
// 3 barriers/k-tile; rel shift via LDS Rbuf (round-5 proven, no spill).
// ---------------------------------------------------------------------------
__global__ __launch_bounds__(256, 3) void attn_mfma(
    const float* __restrict__ tmpQ,                 // [b*T+t][512] fp32
    const float* __restrict__ rwb,                  // [512]
    const float* __restrict__ rrb,                  // [512]
    const __hip_bfloat16* __restrict__ Kbf,         // [b*T+t][512] bf16
    const __hip_bfloat16* __restrict__ rKl,         // [h*3071+l][64] bf16
    const __hip_bfloat16* __restrict__ Vtg,         // [(b*8+h)*192+v][1536] bf16
    __hip_bfloat16* __restrict__ O)                 // [b*T+q][1536] bf16
{
  const int tid = threadIdx.x;
  const int w = tid >> 6, lane = tid & 63;
  const int quad = lane >> 4, l16 = lane & 15;
  const int bid = blockIdx.x;
  const int qt = bid % 24;
  const int h = (bid / 24) & 7;
  const int b = bid / 192;
  const int q0 = qt * 64;

  // LDS: Ktile 64x68 (8704 B) @0 ; rKwin 128x68 (17408 B) @8704 ;
  //      Vtile 192x68 (26112 B) @26112.  Total 52224 -> 3 blocks/CU.
  //      Ptile aliases Ktile; Rbuf[64][132] (16896 B) aliases rKwin (post-B3).
  __shared__ __align__(16) char sm[52224];
  __hip_bfloat16* Ktile = (__hip_bfloat16*)sm;
  __hip_bfloat16* Ptile = (__hip_bfloat16*)sm;
  __hip_bfloat16* rKwin = (__hip_bfloat16*)(sm + 8704);
  __hip_bfloat16* Rbuf  = (__hip_bfloat16*)(sm + 8704);
  __hip_bfloat16* Vtile = (__hip_bfloat16*)(sm + 26112);

  // Q fragments (A-layout): lane holds A[m=l16][k=quad*8+j], kstep*32 offset.
  short8 aQw[2], aQr[2];
  {
    const int qrow = q0 + w * 16 + l16;
    const float* qp = tmpQ + (size_t)(b * TT + qrow) * 512 + h * 64;
#pragma unroll
    for (int ks = 0; ks < 2; ++ks) {
#pragma unroll
      for (int j = 0; j < 8; ++j) {
        const int d = ks * 32 + quad * 8 + j;
        const float qv = qp[d] * 0.125f;
        aQw[ks][j] = f2bf(qv + rwb[h * 64 + d]);
        aQr[ks][j] = f2bf(qv + rrb[h * 64 + d]);
      }
    }
  }

  const floatx4 vzero = {0.f, 0.f, 0.f, 0.f};
  floatx4 Oacc[12];
#pragma unroll
  for (int i = 0; i < 12; ++i) Oacc[i] = vzero;
  float mrow[4], lrow[4];
#pragma unroll
  for (int r = 0; r < 4; ++r) { mrow[r] = -INFINITY; lrow[r] = 0.f; }

  const size_t kBase = (size_t)(b * TT) * 512 + h * 64;
  const __hip_bfloat16* VtgB = Vtg + ((size_t)(b * 8 + h) * 192) * 1536;
  const int l0base = 1472 - q0;   // l = l0base + k0 + j

  for (int k0 = 0; k0 < TT; k0 += 64) {
    __syncthreads();  // B1: prev-iter Ptile/Vtile reads done
    {   // stage Ktile (64x64, stride 68)
      const int r = tid >> 2, c0 = (tid & 3) * 16;
      const __hip_bfloat16* src = Kbf + kBase + (size_t)(k0 + r) * 512 + c0;
      *(uint4*)(Ktile + r * 68 + c0)     = *(const uint4*)(src);
      *(uint4*)(Ktile + r * 68 + c0 + 8) = *(const uint4*)(src + 8);
    }
    {   // stage rKwin (128x64, stride 68)
      const int r = tid >> 1, c0 = (tid & 1) * 32;
      int l = l0base + k0 + r;
      l = l < 3070 ? l : 3070;   // rows with j>126 never consumed; clamp
      const __hip_bfloat16* src = rKl + ((size_t)h * LREL + l) * 64 + c0;
#pragma unroll
      for (int u = 0; u < 4; ++u)
        *(uint4*)(rKwin + r * 68 + c0 + u * 8) = *(const uint4*)(src + u * 8);
    }
    {   // stage Vtile (192x64, stride 68) — full DV in one pass
      for (int i = tid; i < 192 * 8; i += 256) {
        const int r = i >> 3, c0 = (i & 7) * 8;
        *(uint4*)(Vtile + r * 68 + c0) =
            *(const uint4*)(VtgB + (size_t)r * 1536 + k0 + c0);
      }
    }
    __syncthreads();  // B2: tiles visible

    floatx4 S[4], R[8];
#pragma unroll
    for (int i = 0; i < 4; ++i) S[i] = vzero;
#pragma unroll
    for (int i = 0; i < 8; ++i) R[i] = vzero;
#pragma unroll
    for (int kt = 0; kt < 4; ++kt) {
#pragma unroll
      for (int ks = 0; ks < 2; ++ks) {
        short8 bK = *(const short8*)(Ktile + (kt * 16 + l16) * 68 + ks * 32 + quad * 8);
        S[kt] = __builtin_amdgcn_mfma_f32_16x16x32_bf16(aQw[ks], bK, S[kt], 0, 0, 0);
      }
    }
#pragma unroll
    for (int jt = 0; jt < 8; ++jt) {
#pragma unroll
      for (int ks = 0; ks < 2; ++ks) {
        short8 bR = *(const short8*)(rKwin + (jt * 16 + l16) * 68 + ks * 32 + quad * 8);
        R[jt] = __builtin_amdgcn_mfma_f32_16x16x32_bf16(aQr[ks], bR, R[jt], 0, 0, 0);
      }
    }
    __syncthreads();  // B3: all K/rK frag reads done; Rbuf/Ptile aliases live

    // write R (wave-private rows), then gather the diagonal shift
    // (intra-wave LDS write->read: DS ops from one wave are processed in order)
#pragma unroll
    for (int jt = 0; jt < 8; ++jt) {
#pragma unroll
      for (int r = 0; r < 4; ++r) {
        const int row = w * 16 + quad * 4 + r;
        Rbuf[row * 132 + jt * 16 + l16] = __float2bfloat16(R[jt][r]);
      }
    }
#pragma unroll
    for (int kt = 0; kt < 4; ++kt) {
#pragma unroll
      for (int r = 0; r < 4; ++r) {
        const int row = w * 16 + quad * 4 + r;
        const int j = kt * 16 + l16 + 63 - row;   // in [0,126]
        S[kt][r] += (float)Rbuf[row * 132 + j];
      }
    }

    // online softmax (rows wave-private; 16 lanes share a row)
    float alpha[4];
#pragma unroll
    for (int r = 0; r < 4; ++r) {
      float mx = fmaxf(fmaxf(S[0][r], S[1][r]), fmaxf(S[2][r], S[3][r]));
#pragma unroll
      for (int off = 8; off > 0; off >>= 1) mx = fmaxf(mx, __shfl_xor(mx, off));
      const float nm = fmaxf(mrow[r], mx);
      alpha[r] = __expf(mrow[r] - nm);
      mrow[r] = nm;
      float ps = 0.f;
#pragma unroll
      for (int kt = 0; kt < 4; ++kt) {
        const float p = __expf(S[kt][r] - nm);
        S[kt][r] = p;
        ps += p;
      }
#pragma unroll
      for (int off = 8; off > 0; off >>= 1) ps += __shfl_xor(ps, off);
      lrow[r] = lrow[r] * alpha[r] + ps;
    }

    // write P (wave-private rows; aP read below is same-wave, DS in-order)
#pragma unroll
    for (int kt = 0; kt < 4; ++kt) {
#pragma unroll
      for (int r = 0; r < 4; ++r) {
        const int row = w * 16 + quad * 4 + r;
        Ptile[row * 68 + kt * 16 + l16] = __float2bfloat16(S[kt][r]);
      }
    }
#pragma unroll
    for (int vt = 0; vt < 12; ++vt)
#pragma unroll
      for (int r = 0; r < 4; ++r) Oacc[vt][r] *= alpha[r];

    short8 aP[2];
#pragma unroll
    for (int ks = 0; ks < 2; ++ks)
      aP[ks] = *(const short8*)(Ptile + (w * 16 + l16) * 68 + ks * 32 + quad * 8);
#pragma unroll
    for (int vt = 0; vt < 12; ++vt) {
#pragma unroll
      for (int ks = 0; ks < 2; ++ks) {
        short8 bV = *(const short8*)(Vtile + (vt * 16 + l16) * 68 + ks * 32 + quad * 8);
        Oacc[vt] = __builtin_amdgcn_mfma_f32_16x16x32_bf16(aP[ks], bV, Oacc[vt], 0, 0, 0);
      }
    }
  }

  // epilogue: normalize, store bf16 (feeds MFMA out-projection)
#pragma unroll
  for (int r = 0; r < 4; ++r) {
    const float inv = 1.f / lrow[r];
    const int qrow = q0 + w * 16 + quad * 4 + r;
    __hip_bfloat16* op = O + (size_t)(b * TT + qrow) * 1536 + h * 192;
#pragma unroll
    for (int vt = 0; vt < 12; ++vt)
      op[vt * 16 + l16] = __float2bfloat16(Oacc[vt][r] * inv);
  }
}

// ---------------------------------------------------------------------------
extern "C" void kernel_launch(void* const* d_in, const int* in_sizes, int n_in,
                              void* d_out, int out_size, void* d_ws, size_t ws_size,
                              hipStream_t stream) {
  const void* x     = d_in[0];
  const void* W_q   = d_in[1];
  const void* W_k   = d_in[2];
  const void* W_v   = d_in[3];
  const void* W_rel = d_in[4];
  const void* W_out = d_in[5];
  const void* b_out = d_in[6];
  const void* r_w_b = d_in[7];
  const void* r_r_b = d_in[8];

  float* ws = (float*)d_ws;
  int*    flag = (int*)d_ws;                     // 16 floats reserved
  double* gmax = (double*)(ws + 16);             // 64 floats
  float* pe    = ws + 16 + 64;                   // 3071*192
  float* WrelF = pe    + (size_t)LREL * 192;     // 192*512
  float* boutF = WrelF + (size_t)192 * 512;      // 1536
  float* rwbF  = boutF + 1536;                   // 512
  float* rrbF  = rwbF + 512;                     // 512
  float* tmpQ  = rrbF + 512;                     // 6144*512 fp32
  __hip_bfloat16* xBf  = (__hip_bfloat16*)(tmpQ + (size_t)MROWS * 512);  // 6144*1536
  __hip_bfloat16* WqT  = xBf  + (size_t)MROWS * 1536;     // 512*1536
  __hip_bfloat16* WkT  = WqT  + (size_t)512 * 1536;       // 512*1536
  __hip_bfloat16* WvT  = WkT  + (size_t)512 * 1536;       // 1536*1536
  __hip_bfloat16* WoT  = WvT  + (size_t)1536 * 1536;      // 1536*1536
  __hip_bfloat16* Kbf  = WoT  + (size_t)1536 * 1536;      // 6144*512
  __hip_bfloat16* Vbf  = Kbf  + (size_t)MROWS * 512;      // 6144*1536
  __hip_bfloat16* Vtg  = Vbf  + (size_t)MROWS * 1536;     // 32*192*1536
  __hip_bfloat16* Obf  = Vtg  + (size_t)32 * 192 * 1536;  // 6144*1536
  __hip_bfloat16* rKl  = Obf  + (size_t)MROWS * 1536;     // 8*3071*64
  char* endp = (char*)(rKl + (size_t)HH * LREL * 64);
  if (ws_size < (size_t)(endp - (char*)d_ws)) return;  // ws too small

  detect_kernel<<<1, 64, 0, stream>>>(x, flag);

  auto conv = [&](const void* src, float* dst, int n) {
    convert_kernel<<<(n + 255) / 256, 256, 0, stream>>>(src, dst, n, flag);
  };
  conv(W_rel, WrelF, 192 * 512);
  conv(b_out, boutF, 1536);
  conv(r_w_b, rwbF,  512);
  conv(r_r_b, rrbF,  512);

  convbf_kernel<<<(MROWS * 1536 + 255) / 256, 256, 0, stream>>>(x, xBf, MROWS * 1536, flag);

  // weight transposes: src [K,N] -> dst [N,K] bf16
  wt_kernel<<<dim3(512 / 64, 1536 / 64), 256, 0, stream>>>(W_q, WqT, 1536, 512, flag);
  wt_kernel<<<dim3(512 / 64, 1536 / 64), 256, 0, stream>>>(W_k, WkT, 1536, 512, flag);
  wt_kernel<<<dim3(1536 / 64, 1536 / 64), 256, 0, stream>>>(W_v, WvT, 1536, 1536, flag);
  wt_kernel<<<dim3(1536 / 64, 1536 / 64), 256, 0, stream>>>(W_out, WoT, 1536, 1536, flag);

  gmax_kernel<<<32, 256, 0, stream>>>(gmax);
  pe_kernel<<<LREL, 192, 0, stream>>>(pe, gmax);
  relk_kernel<<<(LREL + 7) / 8, 512, 0, stream>>>(pe, WrelF, rKl);

  // projections (bf16 MFMA)
  gemm_mfma<0, false><<<dim3(512 / 128, MROWS / 128), 256, 0, stream>>>(
      xBf, WqT, tmpQ, nullptr, MROWS, 512, CC, flag);
  gemm_mfma<1, false><<<dim3(512 / 128, MROWS / 128), 256, 0, stream>>>(
      xBf, WkT, Kbf, nullptr, MROWS, 512, CC, flag);
  gemm_mfma<1, false><<<dim3(1536 / 128, MROWS / 128), 256, 0, stream>>>(
      xBf, WvT, Vbf, nullptr, MROWS, 1536, CC, flag);

  vtrans_kernel<<<2304, 256, 0, stream>>>(Vbf, Vtg);

  attn_mfma<<<768, 256, 0, stream>>>(tmpQ, rwbF, rrbF, Kbf, rKl, Vtg, Obf);

  gemm_mfma<2, true><<<dim3(1536 / 128, MROWS / 128), 256, 0, stream>>>(
      Obf, WoT, d_out, boutF, MROWS, 1536, CC, flag);
}

// Round 8
// 514.278 us; speedup vs baseline: 1.8084x; 1.7763x over previous
//
#include <hip/hip_runtime.h>
#include <hip/hip_bf16.h>
#include <math.h>

// Problem constants
#define BB 4
#define TT 1536
#define CC 1536
#define HH 8
#define DKk 64
#define DVv 192
#define NBASIS 32
#define LREL 3071          // 2T-1
#define MROWS 6144         // B*T

typedef short short8 __attribute__((ext_vector_type(8)));
typedef float floatx4 __attribute__((ext_vector_type(4)));

static __device__ inline short f2bf(float f) {
  __hip_bfloat16 h = __float2bfloat16(f);
  return *reinterpret_cast<short*>(&h);
}

// async global->LDS, 16B per lane; LDS dest = wave-uniform base + lane*16
static __device__ inline void gload_lds16(const __hip_bfloat16* g, __hip_bfloat16* l) {
  __builtin_amdgcn_global_load_lds(
      (const __attribute__((address_space(1))) unsigned int*)g,
      (__attribute__((address_space(3))) unsigned int*)l, 16, 0, 0);
}

// ---------------------------------------------------------------------------
// Stage 0: dtype detection (fp32 vs bf16 input payloads). See round-1 notes.
// ---------------------------------------------------------------------------
__global__ void detect_kernel(const void* __restrict__ x, int* __restrict__ flag) {
  if (threadIdx.x == 0 && blockIdx.x == 0) {
    const __hip_bfloat16* h = (const __hip_bfloat16*)x;
    int cnt = 0;
    for (int i = 0; i < 64; ++i) {
      float v = fabsf((float)h[2 * i]);
      if (v > 1e-5f && v < 256.0f) cnt++;
    }
    *flag = (cnt >= 32) ? 1 : 0;  // 1 => inputs are bf16
  }
}

__global__ __launch_bounds__(256) void convert_kernel(const void* __restrict__ src,
                                                      float* __restrict__ dst, int n,
                                                      const int* __restrict__ flag) {
  const int i = blockIdx.x * 256 + threadIdx.x;
  if (i >= n) return;
  if (*flag) dst[i] = (float)((const __hip_bfloat16*)src)[i];
  else       dst[i] = ((const float*)src)[i];
}

__global__ __launch_bounds__(256) void convbf_kernel(const void* __restrict__ src,
                                                     __hip_bfloat16* __restrict__ dst, int n,
                                                     const int* __restrict__ flag) {
  const int i = blockIdx.x * 256 + threadIdx.x;
  if (i >= n) return;
  if (*flag) dst[i] = ((const __hip_bfloat16*)src)[i];
  else       dst[i] = __float2bfloat16(((const float*)src)[i]);
}

// ---------------------------------------------------------------------------
// Weight transpose: src [K,N] (fp32/bf16 per flag) -> dst bf16 [N,K]
// ---------------------------------------------------------------------------
__global__ __launch_bounds__(256) void wt_kernel(const void* __restrict__ src,
                                                 __hip_bfloat16* __restrict__ dst,
                                                 int K, int N, const int* __restrict__ flag) {
  __shared__ __hip_bfloat16 tile[64][68];
  const int tid = threadIdx.x;
  const int k0 = blockIdx.y * 64, n0 = blockIdx.x * 64;
  const bool bf = (*flag != 0);
  {
    const int r = tid >> 2, c0 = (tid & 3) * 16;
    if (bf) {
      const __hip_bfloat16* sp = (const __hip_bfloat16*)src + (size_t)(k0 + r) * N + n0 + c0;
#pragma unroll
      for (int u = 0; u < 16; ++u) tile[r][c0 + u] = sp[u];
    } else {
      const float* sp = (const float*)src + (size_t)(k0 + r) * N + n0 + c0;
#pragma unroll
      for (int u = 0; u < 16; ++u) tile[r][c0 + u] = __float2bfloat16(sp[u]);
    }
  }
  __syncthreads();
  {
    const int nr = tid >> 2, c0 = (tid & 3) * 16;
    __hip_bfloat16* dp = dst + (size_t)(n0 + nr) * K + k0 + c0;
#pragma unroll
    for (int u = 0; u < 16; ++u) dp[u] = tile[c0 + u][nr];
  }
}

// ---------------------------------------------------------------------------
// Stage 1: gamma-basis max over pos (fp64). One block per basis j.
// ---------------------------------------------------------------------------
__global__ void gmax_kernel(double* __restrict__ gmax) {
  const int j = blockIdx.x;
  const double mean = 48.0 + 1488.0 * (double)j / 31.0;
  const double conc = (mean / 24.0) * (mean / 24.0);
  const double rate = mean / 576.0;
  const double log_norm = lgamma(conc) - conc * log(rate);
  double mx = 1e-8;
  for (int pos = 1 + threadIdx.x; pos <= 1535; pos += 256) {
    double p = exp((conc - 1.0) * log((double)pos) - rate * (double)pos - log_norm) + 1e-8;
    mx = fmax(mx, p);
  }
  __shared__ double red[256];
  red[threadIdx.x] = mx;
  __syncthreads();
  for (int s = 128; s > 0; s >>= 1) {
    if (threadIdx.x < s) red[threadIdx.x] = fmax(red[threadIdx.x], red[threadIdx.x + s]);
    __syncthreads();
  }
  if (threadIdx.x == 0) gmax[j] = red[0];
}

// ---------------------------------------------------------------------------
// Stage 2: pe[l, f], fp64 math, fp32 store.
// ---------------------------------------------------------------------------
__global__ void pe_kernel(float* __restrict__ pe, const double* __restrict__ gmax) {
  const int l = blockIdx.x;
  const int f = threadIdx.x;  // 0..191
  const int dist = l - (TT - 1);
  const int pos = dist < 0 ? -dist : dist;
  const int base = f % 96;
  const int cls = base / 32;
  const int j = base % 32;
  double v;
  if (cls == 0) {
    const double max_range = log(1536.0) / log(2.0);
    const double e = 3.0 + (max_range - 3.0) * (double)j / 31.0;
    const double hl = exp2(e);
    v = exp2(-(double)pos / hl);
  } else if (cls == 1) {
    const double width = exp2((double)(j + 1)) - 1.0;
    v = (width > (double)pos) ? 1.0 : 0.0;
  } else {
    const double mean = 48.0 + 1488.0 * (double)j / 31.0;
    const double conc = (mean / 24.0) * (mean / 24.0);
    const double rate = mean / 576.0;
    double p;
    if (pos == 0) {
      p = 1e-8;
    } else {
      const double log_norm = lgamma(conc) - conc * log(rate);
      p = exp((conc - 1.0) * log((double)pos) - rate * (double)pos - log_norm) + 1e-8;
    }
    v = p / gmax[j];
  }
  float out = (float)v;
  if (f >= 96) {
    float sgn = (dist > 0) ? 1.f : (dist < 0 ? -1.f : 0.f);
    out *= sgn;
  }
  pe[(size_t)l * 192 + f] = out;
}

// ---------------------------------------------------------------------------
// Stage 3: rKl[h][l][d] (bf16) = sum_f pe[l,f] * W_rel_k[f, h*64+d]
// ---------------------------------------------------------------------------
__global__ __launch_bounds__(512) void relk_kernel(const float* __restrict__ pe,
                                                   const float* __restrict__ Wrk,
                                                   __hip_bfloat16* __restrict__ rKl) {
  __shared__ float pes[8][192];
  const int l0 = blockIdx.x * 8;
  const int nrows = (LREL - l0) < 8 ? (LREL - l0) : 8;
  const int tid = threadIdx.x;
  for (int idx = tid; idx < nrows * 192; idx += 512) {
    int r = idx / 192, f = idx % 192;
    pes[r][f] = pe[(size_t)(l0 + r) * 192 + f];
  }
  __syncthreads();
  float acc[8] = {0.f, 0.f, 0.f, 0.f, 0.f, 0.f, 0.f, 0.f};
  for (int f = 0; f < 192; ++f) {
    float w = Wrk[(size_t)f * 512 + tid];
#pragma unroll
    for (int r = 0; r < 8; ++r) acc[r] += pes[r][f] * w;
  }
  const int h = tid >> 6, d = tid & 63;
  for (int r = 0; r < nrows; ++r)
    rKl[((size_t)h * LREL + (l0 + r)) * 64 + d] = __float2bfloat16(acc[r]);
}

// ---------------------------------------------------------------------------
// bf16 MFMA GEMM (m97 structure): C[M,N] = A[M,K] @ Bt[N,K]^T
// 128x128 tile, BK=32, 4 waves, global_load_lds staging, ds_read_b128 frags.
// MODE 0: fp32 out; 1: bf16 out; 2: d_out per flag (+bias);
// MODE 3: fused QK — cols<512 -> fp32 Cout (N=512), cols>=512 -> bf16 Cout2.
// ---------------------------------------------------------------------------
template <int MODE, bool BIAS>
__global__ __launch_bounds__(256) void gemm_mfma(const __hip_bfloat16* __restrict__ A,
                                                 const __hip_bfloat16* __restrict__ Bt,
                                                 void* __restrict__ Cout,
                                                 void* __restrict__ Cout2,
                                                 const float* __restrict__ bias,
                                                 int M, int N, int K,
                                                 const int* __restrict__ flag) {
  __shared__ __align__(16) __hip_bfloat16 As[128 * 32];
  __shared__ __align__(16) __hip_bfloat16 Bs[128 * 32];
  const int tid = threadIdx.x;
  const int w = tid >> 6, lane = tid & 63;
  const int quad = lane >> 4, l16 = lane & 15;
  const int wm = w >> 1, wn = w & 1;
  const int row0 = blockIdx.y * 128, col0 = blockIdx.x * 128;

  const floatx4 vzero = {0.f, 0.f, 0.f, 0.f};
  floatx4 acc[4][4];
#pragma unroll
  for (int i = 0; i < 4; ++i)
#pragma unroll
    for (int j = 0; j < 4; ++j) acc[i][j] = vzero;

  const int sr = lane >> 2;            // 0..15
  const int sc = (lane & 3) * 8;       // bf16 elems
  const __hip_bfloat16* ag0 = A + (size_t)(row0 + w * 32 + sr) * K + sc;
  const __hip_bfloat16* ag1 = A + (size_t)(row0 + w * 32 + 16 + sr) * K + sc;
  const __hip_bfloat16* bg0 = Bt + (size_t)(col0 + w * 32 + sr) * K + sc;
  const __hip_bfloat16* bg1 = Bt + (size_t)(col0 + w * 32 + 16 + sr) * K + sc;
  __hip_bfloat16* as0 = As + w * 32 * 32;
  __hip_bfloat16* as1 = As + (w * 32 + 16) * 32;
  __hip_bfloat16* bs0 = Bs + w * 32 * 32;
  __hip_bfloat16* bs1 = Bs + (w * 32 + 16) * 32;

  for (int k0 = 0; k0 < K; k0 += 32) {
    __syncthreads();
    gload_lds16(ag0 + k0, as0);
    gload_lds16(ag1 + k0, as1);
    gload_lds16(bg0 + k0, bs0);
    gload_lds16(bg1 + k0, bs1);
    __syncthreads();
    short8 aF[4], bF[4];
#pragma unroll
    for (int mt = 0; mt < 4; ++mt)
      aF[mt] = *(const short8*)(As + (wm * 64 + mt * 16 + l16) * 32 + quad * 8);
#pragma unroll
    for (int nt = 0; nt < 4; ++nt)
      bF[nt] = *(const short8*)(Bs + (wn * 64 + nt * 16 + l16) * 32 + quad * 8);
#pragma unroll
    for (int mt = 0; mt < 4; ++mt)
#pragma unroll
      for (int nt = 0; nt < 4; ++nt)
        acc[mt][nt] = __builtin_amdgcn_mfma_f32_16x16x32_bf16(aF[mt], bF[nt], acc[mt][nt], 0, 0, 0);
  }

  const bool obf = (MODE == 2) ? (*flag != 0) : false;
#pragma unroll
  for (int mt = 0; mt < 4; ++mt) {
#pragma unroll
    for (int r = 0; r < 4; ++r) {
      const int row = row0 + wm * 64 + mt * 16 + quad * 4 + r;
#pragma unroll
      for (int nt = 0; nt < 4; ++nt) {
        const int col = col0 + wn * 64 + nt * 16 + l16;
        float v = acc[mt][nt][r];
        if (BIAS) v += bias[col];
        if (MODE == 0) {
          ((float*)Cout)[(size_t)row * N + col] = v;
        } else if (MODE == 1) {
          ((__hip_bfloat16*)Cout)[(size_t)row * N + col] = __float2bfloat16(v);
        } else if (MODE == 2) {
          if (obf) ((__hip_bfloat16*)Cout)[(size_t)row * N + col] = __float2bfloat16(v);
          else     ((float*)Cout)[(size_t)row * N + col] = v;
        } else {  // MODE 3: fused Q (fp32) / K (bf16), each N=512
          if (col < 512)
            ((float*)Cout)[(size_t)row * 512 + col] = v;
          else
            ((__hip_bfloat16*)Cout2)[(size_t)row * 512 + (col - 512)] = __float2bfloat16(v);
        }
      }
    }
  }
}

// ---------------------------------------------------------------------------
// V transpose: Vbf bf16 [b*T+t][h*192+v] -> Vtg bf16 [(b*8+h)*192 + v][1536 t]
// ---------------------------------------------------------------------------
__global__ __launch_bounds__(256) void vtrans_kernel(const __hip_bfloat16* __restrict__ Vbf,
                                                     __hip_bfloat16* __restrict__ Vtg) {
  int bid = blockIdx.x;            // 4*8*24*3 = 2304
  int vt = bid % 3; int tt = (bid / 3) % 24; int h = (bid / 72) & 7; int b = bid / 576;
  __shared__ __hip_bfloat16 tile[64][72];
  const int tid = threadIdx.x;
  {
    int r = tid >> 2, c0 = (tid & 3) * 16;   // r: t-row, c: v-col
    const __hip_bfloat16* src = Vbf + (size_t)(b * TT + tt * 64 + r) * 1536 + h * 192 + vt * 64 + c0;
#pragma unroll
    for (int u = 0; u < 16; ++u) tile[r][c0 + u] = src[u];
  }
  __syncthreads();
  {
    int vr = tid >> 2, t0 = (tid & 3) * 16;
    __hip_bfloat16* dst = Vtg + ((size_t)((b * 8 + h) * 192) + vt * 64 + vr) * 1536 + tt * 64 + t0;
    union { uint4 u4[2]; unsigned short us[16]; } pk;
#pragma unroll
    for (int u = 0; u < 16; ++u) pk.us[u] = *(const unsigned short*)&tile[t0 + u][vr];
    *(uint4*)(dst) = pk.u4[0];
    *(uint4*)(dst + 8) = pk.u4[1];
  }
}

// ---------------------------------------------------------------------------
// MFMA flash attention — round-5 proven config (184 us): stride-72 tiles
// (16B-aligned rows), LDS Rbuf shift-gather, two-half V staging, 5 barriers.
// ---------------------------------------------------------------------------
__global__ __launch_bounds__(256, 3) void attn_mfma(
    const float* __restrict__ tmpQ,                 // [b*T+t][512] fp32
    const float* __restrict__ rwb,                  // [512]
    const float* __restrict__ rrb,                  // [512]
    const __hip_bfloat16* __restrict__ Kbf,         // [b*T+t][512] bf16
    const __hip_bfloat16* __restrict__ rKl,         // [h*3071+l][64] bf16
    const __hip_bfloat16* __restrict__ Vtg,         // [(b*8+h)*192+v][1536] bf16
    __hip_bfloat16* __restrict__ O)                 // [b*T+q][1536] bf16
{
  const int tid = threadIdx.x;
  const int w = tid >> 6, lane = tid & 63;
  const int quad = lane >> 4, l16 = lane & 15;
  const int bid = blockIdx.x;
  const int qt = bid % 24;
  const int h = (bid / 24) & 7;
  const int b = bid / 192;
  const int q0 = qt * 64;

  // LDS (bytes): Ktile[64][72] @0 (9216) ; rKwin[128][72] @9216 (18432);
  //   Rbuf[64][132] aliases rKwin ; Ptile aliases Ktile ;
  //   Vtile[96][72] @27648 (13824).  Total 41472 -> 3 blocks/CU.
  __shared__ __align__(16) char sm[41472];
  __hip_bfloat16* Ktile = (__hip_bfloat16*)sm;
  __hip_bfloat16* rKwin = (__hip_bfloat16*)(sm + 9216);
  __hip_bfloat16* Rbuf  = (__hip_bfloat16*)(sm + 9216);
  __hip_bfloat16* Ptile = (__hip_bfloat16*)sm;
  __hip_bfloat16* Vtile = (__hip_bfloat16*)(sm + 27648);

  // Q fragments (A-layout): lane holds A[m=l16][k=quad*8+j], kstep*32 offset.
  short8 aQw[2], aQr[2];
  {
    const int qrow = q0 + w * 16 + l16;
    const float* qp = tmpQ + (size_t)(b * TT + qrow) * 512 + h * 64;
#pragma unroll
    for (int ks = 0; ks < 2; ++ks) {
#pragma unroll
      for (int j = 0; j < 8; ++j) {
        const int d = ks * 32 + quad * 8 + j;
        const float qv = qp[d] * 0.125f;
        aQw[ks][j] = f2bf(qv + rwb[h * 64 + d]);
        aQr[ks][j] = f2bf(qv + rrb[h * 64 + d]);
      }
    }
  }

  const floatx4 vzero = {0.f, 0.f, 0.f, 0.f};
  floatx4 Oacc[12];
#pragma unroll
  for (int i = 0; i < 12; ++i) Oacc[i] = vzero;
  float mrow[4], lrow[4];
#pragma unroll
  for (int r = 0; r < 4; ++r) { mrow[r] = -INFINITY; lrow[r] = 0.f; }

  const size_t kBase = (size_t)(b * TT) * 512 + h * 64;
  const __hip_bfloat16* VtgB = Vtg + ((size_t)(b * 8 + h) * 192) * 1536;
  const int l0base = 1472 - q0;   // l = l0base + k0 + j

  for (int k0 = 0; k0 < TT; k0 += 64) {
    __syncthreads();  // B1: prev-iter P/Vtile reads done
    {   // stage Ktile (64 x 64, stride 72)
      const int r = tid >> 2, c0 = (tid & 3) * 16;
      const __hip_bfloat16* src = Kbf + kBase + (size_t)(k0 + r) * 512 + c0;
      *(uint4*)(Ktile + r * 72 + c0)     = *(const uint4*)(src);
      *(uint4*)(Ktile + r * 72 + c0 + 8) = *(const uint4*)(src + 8);
    }
    {   // stage rKwin (128 x 64, stride 72)
      const int r = tid >> 1, c0 = (tid & 1) * 32;
      int l = l0base + k0 + r;
      l = l < 3070 ? l : 3070;   // rows with j>126 never consumed; clamp
      const __hip_bfloat16* src = rKl + ((size_t)h * LREL + l) * 64 + c0;
#pragma unroll
      for (int u = 0; u < 4; ++u)
        *(uint4*)(rKwin + r * 72 + c0 + u * 8) = *(const uint4*)(src + u * 8);
    }
    {   // stage Vtile half0 (v 0..95): full 64 cols
      for (int i = tid; i < 96 * 8; i += 256) {
        const int r = i >> 3, c0 = (i & 7) * 8;
        *(uint4*)(Vtile + r * 72 + c0) =
            *(const uint4*)(VtgB + (size_t)r * 1536 + k0 + c0);
      }
    }
    __syncthreads();  // B2: tiles visible

    floatx4 S[4], R[8];
#pragma unroll
    for (int i = 0; i < 4; ++i) S[i] = vzero;
#pragma unroll
    for (int i = 0; i < 8; ++i) R[i] = vzero;
#pragma unroll
    for (int kt = 0; kt < 4; ++kt) {
#pragma unroll
      for (int ks = 0; ks < 2; ++ks) {
        short8 bK = *(const short8*)(Ktile + (kt * 16 + l16) * 72 + ks * 32 + quad * 8);
        S[kt] = __builtin_amdgcn_mfma_f32_16x16x32_bf16(aQw[ks], bK, S[kt], 0, 0, 0);
      }
    }
#pragma unroll
    for (int jt = 0; jt < 8; ++jt) {
#pragma unroll
      for (int ks = 0; ks < 2; ++ks) {
        short8 bR = *(const short8*)(rKwin + (jt * 16 + l16) * 72 + ks * 32 + quad * 8);
        R[jt] = __builtin_amdgcn_mfma_f32_16x16x32_bf16(aQr[ks], bR, R[jt], 0, 0, 0);
      }
    }
    __syncthreads();  // B3: all K/rK reads done; Rbuf/Ptile writes may begin

    // write R (wave-private rows), then gather the diagonal shift
    // (intra-wave LDS write->read: DS ops from one wave are processed in order)
#pragma unroll
    for (int jt = 0; jt < 8; ++jt) {
#pragma unroll
      for (int r = 0; r < 4; ++r) {
        const int row = w * 16 + quad * 4 + r;
        Rbuf[row * 132 + jt * 16 + l16] = __float2bfloat16(R[jt][r]);
      }
    }
#pragma unroll
    for (int kt = 0; kt < 4; ++kt) {
#pragma unroll
      for (int r = 0; r < 4; ++r) {
        const int row = w * 16 + quad * 4 + r;
        const int j = kt * 16 + l16 + 63 - row;   // in [0,126]
        S[kt][r] += (float)Rbuf[row * 132 + j];
      }
    }

    // online softmax (rows wave-private; 16 lanes share a row)
    float alpha[4];
#pragma unroll
    for (int r = 0; r < 4; ++r) {
      float mx = fmaxf(fmaxf(S[0][r], S[1][r]), fmaxf(S[2][r], S[3][r]));
#pragma unroll
      for (int off = 8; off > 0; off >>= 1) mx = fmaxf(mx, __shfl_xor(mx, off));
      const float nm = fmaxf(mrow[r], mx);
      alpha[r] = __expf(mrow[r] - nm);
      mrow[r] = nm;
      float ps = 0.f;
#pragma unroll
      for (int kt = 0; kt < 4; ++kt) {
        const float p = __expf(S[kt][r] - nm);
        S[kt][r] = p;
        ps += p;
      }
#pragma unroll
      for (int off = 8; off > 0; off >>= 1) ps += __shfl_xor(ps, off);
      lrow[r] = lrow[r] * alpha[r] + ps;
    }
    // write P (A-layout source, wave-private rows), rescale O
#pragma unroll
    for (int kt = 0; kt < 4; ++kt) {
#pragma unroll
      for (int r = 0; r < 4; ++r) {
        const int row = w * 16 + quad * 4 + r;
        Ptile[row * 72 + kt * 16 + l16] = __float2bfloat16(S[kt][r]);
      }
    }
#pragma unroll
    for (int vt = 0; vt < 12; ++vt)
#pragma unroll
      for (int r = 0; r < 4; ++r) Oacc[vt][r] *= alpha[r];

    // PV half 0 (v 0..95)
    short8 aP[2];
#pragma unroll
    for (int ks = 0; ks < 2; ++ks)
      aP[ks] = *(const short8*)(Ptile + (w * 16 + l16) * 72 + ks * 32 + quad * 8);
#pragma unroll
    for (int vt = 0; vt < 6; ++vt) {
#pragma unroll
      for (int ks = 0; ks < 2; ++ks) {
        short8 bV = *(const short8*)(Vtile + (vt * 16 + l16) * 72 + ks * 32 + quad * 8);
        Oacc[vt] = __builtin_amdgcn_mfma_f32_16x16x32_bf16(aP[ks], bV, Oacc[vt], 0, 0, 0);
      }
    }
    __syncthreads();  // B4: PV0 reads done; restage Vtile
    {   // stage Vtile half1 (v 96..191): full 64 cols
      for (int i = tid; i < 96 * 8; i += 256) {
        const int r = i >> 3, c0 = (i & 7) * 8;
        *(uint4*)(Vtile + r * 72 + c0) =
            *(const uint4*)(VtgB + (size_t)(96 + r) * 1536 + k0 + c0);
      }
    }
    __syncthreads();  // B5
#pragma unroll
    for (int vt = 6; vt < 12; ++vt) {
#pragma unroll
      for (int ks = 0; ks < 2; ++ks) {
        short8 bV = *(const short8*)(Vtile + ((vt - 6) * 16 + l16) * 72 + ks * 32 + quad * 8);
        Oacc[vt] = __builtin_amdgcn_mfma_f32_16x16x32_bf16(aP[ks], bV, Oacc[vt], 0, 0, 0);
      }
    }
  }

  // epilogue: normalize, store bf16 (feeds MFMA out-projection)
#pragma unroll
  for (int r = 0; r < 4; ++r) {
    const float inv = 1.f / lrow[r];
    const int qrow = q0 + w * 16 + quad * 4 + r;
    __hip_bfloat16* op = O + (size_t)(b * TT + qrow) * 1536 + h * 192;
#pragma unroll
    for (int vt = 0; vt < 12; ++vt)
      op[vt * 16 + l16] = __float2bfloat16(Oacc[vt][r] * inv);
  }
}

// ---------------------------------------------------------------------------
extern "C" void kernel_launch(void* const* d_in, const int* in_sizes, int n_in,
                              void* d_out, int out_size, void* d_ws, size_t ws_size,
                              hipStream_t stream) {
  const void* x     = d_in[0];
  const void* W_q   = d_in[1];
  const void* W_k   = d_in[2];
  const void* W_v   = d_in[3];
  const void* W_rel = d_in[4];
  const void* W_out = d_in[5];
  const void* b_out = d_in[6];
  const void* r_w_b = d_in[7];
  const void* r_r_b = d_in[8];

  float* ws = (float*)d_ws;
  int*    flag = (int*)d_ws;                     // 16 floats reserved
  double* gmax = (double*)(ws + 16);             // 64 floats
  float* pe    = ws + 16 + 64;                   // 3071*192
  float* WrelF = pe    + (size_t)LREL * 192;     // 192*512
  float* boutF = WrelF + (size_t)192 * 512;      // 1536
  float* rwbF  = boutF + 1536;                   // 512
  float* rrbF  = rwbF + 512;                     // 512
  float* tmpQ  = rrbF + 512;                     // 6144*512 fp32
  __hip_bfloat16* xBf  = (__hip_bfloat16*)(tmpQ + (size_t)MROWS * 512);  // 6144*1536
  __hip_bfloat16* WqT  = xBf  + (size_t)MROWS * 1536;     // 512*1536
  __hip_bfloat16* WkT  = WqT  + (size_t)512 * 1536;       // 512*1536 (contiguous after WqT!)
  __hip_bfloat16* WvT  = WkT  + (size_t)512 * 1536;       // 1536*1536
  __hip_bfloat16* WoT  = WvT  + (size_t)1536 * 1536;      // 1536*1536
  __hip_bfloat16* Kbf  = WoT  + (size_t)1536 * 1536;      // 6144*512
  __hip_bfloat16* Vbf  = Kbf  + (size_t)MROWS * 512;      // 6144*1536
  __hip_bfloat16* Vtg  = Vbf  + (size_t)MROWS * 1536;     // 32*192*1536
  __hip_bfloat16* Obf  = Vtg  + (size_t)32 * 192 * 1536;  // 6144*1536
  __hip_bfloat16* rKl  = Obf  + (size_t)MROWS * 1536;     // 8*3071*64
  char* endp = (char*)(rKl + (size_t)HH * LREL * 64);
  if (ws_size < (size_t)(endp - (char*)d_ws)) return;  // ws too small

  detect_kernel<<<1, 64, 0, stream>>>(x, flag);

  auto conv = [&](const void* src, float* dst, int n) {
    convert_kernel<<<(n + 255) / 256, 256, 0, stream>>>(src, dst, n, flag);
  };
  conv(W_rel, WrelF, 192 * 512);
  conv(b_out, boutF, 1536);
  conv(r_w_b, rwbF,  512);
  conv(r_r_b, rrbF,  512);

  convbf_kernel<<<(MROWS * 1536 + 255) / 256, 256, 0, stream>>>(x, xBf, MROWS * 1536, flag);

  // weight transposes: src [K,N] -> dst [N,K] bf16
  wt_kernel<<<dim3(512 / 64, 1536 / 64), 256, 0, stream>>>(W_q, WqT, 1536, 512, flag);
  wt_kernel<<<dim3(512 / 64, 1536 / 64), 256, 0, stream>>>(W_k, WkT, 1536, 512, flag);
  wt_kernel<<<dim3(1536 / 64, 1536 / 64), 256, 0, stream>>>(W_v, WvT, 1536, 1536, flag);
  wt_kernel<<<dim3(1536 / 64, 1536 / 64), 256, 0, stream>>>(W_out, WoT, 1536, 1536, flag);

  gmax_kernel<<<32, 256, 0, stream>>>(gmax);
  pe_kernel<<<LREL, 192, 0, stream>>>(pe, gmax);
  relk_kernel<<<(LREL + 7) / 8, 512, 0, stream>>>(pe, WrelF, rKl);

  // fused Q+K projection: Bt spans [WqT; WkT] (contiguous), N=1024;
  // cols<512 -> fp32 tmpQ, cols>=512 -> bf16 Kbf (block-uniform branch).
  gemm_mfma<3, false><<<dim3(1024 / 128, MROWS / 128), 256, 0, stream>>>(
      xBf, WqT, tmpQ, Kbf, nullptr, MROWS, 1024, CC, flag);
  gemm_mfma<1, false><<<dim3(1536 / 128, MROWS / 128), 256, 0, stream>>>(
      xBf, WvT, Vbf, nullptr, nullptr, MROWS, 1536, CC, flag);

  vtrans_kernel<<<2304, 256, 0, stream>>>(Vbf, Vtg);

  attn_mfma<<<768, 256, 0, stream>>>(tmpQ, rwbF, rrbF, Kbf, rKl, Vtg, Obf);

  gemm_mfma<2, true><<<dim3(1536 / 128, MROWS / 128), 256, 0, stream>>>(
      Obf, WoT, d_out, nullptr, boutF, MROWS, 1536, CC, flag);
}